// Round 9
// baseline (155.274 us; speedup 1.0000x reference)
//
#include <hip/hip_runtime.h>
#include <cstdint>
#include <cstddef>

#define BB 4
#define CC 256
#define NN 4096
#define CO 32

typedef __attribute__((ext_vector_type(8))) short bf8;
typedef __attribute__((ext_vector_type(4))) float f4;
typedef __attribute__((ext_vector_type(16))) float f16f;
typedef __attribute__((ext_vector_type(2))) unsigned int u32x2;

#define AS1 __attribute__((address_space(1)))
#define AS3 __attribute__((address_space(3)))

__device__ __forceinline__ unsigned short f2bf(float f) {
    union { float f; unsigned int u; } c; c.f = f;
    unsigned int r = c.u + 0x7FFFu + ((c.u >> 16) & 1u);
    return (unsigned short)(r >> 16);
}
__device__ __forceinline__ float bf2f(unsigned short b) {
    union { unsigned int u; float f; } c; c.u = ((unsigned int)b) << 16;
    return c.f;
}
__device__ __forceinline__ unsigned int cvt_pk_bf16(float a, float b) {
    unsigned int r;
    asm("v_cvt_pk_bf16_f32 %0, %1, %2" : "=v"(r) : "v"(a), "v"(b));
    return r;
}

// LDS-only barrier: LDS writes visible WITHOUT draining global loads.
#define LDS_BARRIER()                                          \
    do {                                                       \
        __builtin_amdgcn_sched_barrier(0);                     \
        asm volatile("s_waitcnt lgkmcnt(0)" ::: "memory");     \
        __builtin_amdgcn_s_barrier();                          \
        __builtin_amdgcn_sched_barrier(0);                     \
    } while (0)

// ---------------- kernel 1: fused prep (transpose + QK-proj + V-proj) -------
__global__ __launch_bounds__(512, 2) void k_prep(
        const float* __restrict__ x,
        const float* __restrict__ wq, const float* __restrict__ bq,
        const float* __restrict__ wk, const float* __restrict__ bk,
        const float* __restrict__ wv, const float* __restrict__ bv,
        unsigned short* __restrict__ q_hi, unsigned short* __restrict__ q_lo,
        unsigned short* __restrict__ k_hi, unsigned short* __restrict__ k_lo,
        unsigned short* __restrict__ vws) {
    __shared__ float xT[64 * 256];   // (i,c) at i*256 + ((c>>2)^(i&7))*4 + (c&3)
    int blk = blockIdx.x;
    int it = blk & 63, b = blk >> 6;
    int i0 = it * 64;
    int tid = threadIdx.x, w = tid >> 6, lane = tid & 63;
    int lr = lane & 15, lg = lane >> 4;

    // phase 1: load + swizzled transpose
    {
        const float* xp = x + (size_t)b * CC * NN + i0;
        int cl = tid >> 4;            // 0..31
        int il = (tid & 15) * 4;      // 0..60
#pragma unroll
        for (int pass = 0; pass < 8; ++pass) {
            int c = pass * 32 + cl;
            f4 v = *(const f4*)(xp + (size_t)c * NN + il);
#pragma unroll
            for (int jj = 0; jj < 4; ++jj) {
                int i = il + jj;
                xT[i * 256 + (((c >> 2) ^ (i & 7)) << 2) + (c & 3)] = v[jj];
            }
        }
    }
    __syncthreads();

    if (w < 4) {
        // ---- Q/K projection, wave w -> local i rows [w*16, w*16+16) ----
        f4 acc[4] = {};
        for (int ks = 0; ks < 8; ++ks) {
            int i = w * 16 + lr;
            int kc = ks * 32 + lg * 8;
            f4 xa = *(const f4*)&xT[i * 256 + (((kc >> 2) ^ (i & 7)) << 2)];
            f4 xb = *(const f4*)&xT[i * 256 + ((((kc >> 2) + 1) ^ (i & 7)) << 2)];
            bf8 ahi, alo;
#pragma unroll
            for (int e = 0; e < 8; ++e) {
                float f = (e < 4) ? xa[e] : xb[e - 4];
                unsigned short hh = f2bf(f);
                ahi[e] = (short)hh;
                alo[e] = (short)f2bf(f - bf2f(hh));
            }
#pragma unroll
            for (int u = 0; u < 4; ++u) {
                int o = u * 16 + lr;
                const float* wrow = (u < 2) ? (wq + (size_t)o * CC)
                                            : (wk + (size_t)(o - 32) * CC);
                bf8 bhi, blo;
#pragma unroll
                for (int e = 0; e < 8; ++e) {
                    float wvv = wrow[ks * 32 + lg * 8 + e];
                    unsigned short hh = f2bf(wvv);
                    bhi[e] = (short)hh;
                    blo[e] = (short)f2bf(wvv - bf2f(hh));
                }
                acc[u] = __builtin_amdgcn_mfma_f32_16x16x32_bf16(alo, bhi, acc[u], 0, 0, 0);
                acc[u] = __builtin_amdgcn_mfma_f32_16x16x32_bf16(ahi, blo, acc[u], 0, 0, 0);
                acc[u] = __builtin_amdgcn_mfma_f32_16x16x32_bf16(ahi, bhi, acc[u], 0, 0, 0);
            }
        }
#pragma unroll
        for (int u = 0; u < 4; ++u) {
            int o = u * 16 + lr;
            float bias = (u < 2) ? bq[o] : bk[o - 32];
#pragma unroll
            for (int r = 0; r < 4; ++r) {
                int i = i0 + w * 16 + lg * 4 + r;
                float v = acc[u][r] + bias;
                unsigned short hh = f2bf(v);
                unsigned short ll = f2bf(v - bf2f(hh));
                if (u < 2) {
                    size_t off = ((size_t)b * NN + i) * CO + o;
                    q_hi[off] = hh; q_lo[off] = ll;
                } else {
                    size_t off = ((size_t)b * NN + i) * CO + (o - 32);
                    k_hi[off] = hh; k_lo[off] = ll;
                }
            }
        }
    } else {
        // ---- V projection, wave (w-4) -> c rows [(w-4)*64, +64) ----
        int cb = (w - 4) * 64;
        f4 acc[4][4];   // [u c-sub][t i-sub]
#pragma unroll
        for (int u = 0; u < 4; ++u) {
            f4 bias4;
#pragma unroll
            for (int r = 0; r < 4; ++r) bias4[r] = bv[cb + u * 16 + lg * 4 + r];
#pragma unroll
            for (int t = 0; t < 4; ++t) acc[u][t] = bias4;
        }
        for (int ks = 0; ks < 8; ++ks) {
            bf8 bfr[4];
#pragma unroll
            for (int t = 0; t < 4; ++t) {
                int i = t * 16 + lr;
                int kc = ks * 32 + lg * 8;
                f4 xa = *(const f4*)&xT[i * 256 + (((kc >> 2) ^ (i & 7)) << 2)];
                f4 xb = *(const f4*)&xT[i * 256 + ((((kc >> 2) + 1) ^ (i & 7)) << 2)];
#pragma unroll
                for (int e = 0; e < 8; ++e)
                    bfr[t][e] = (short)f2bf((e < 4) ? xa[e] : xb[e - 4]);
            }
#pragma unroll
            for (int u = 0; u < 4; ++u) {
                const float* wrow = wv + (size_t)(cb + u * 16 + lr) * CC + ks * 32 + lg * 8;
                bf8 afr;
#pragma unroll
                for (int e = 0; e < 8; ++e) afr[e] = (short)f2bf(wrow[e]);
#pragma unroll
                for (int t = 0; t < 4; ++t)
                    acc[u][t] = __builtin_amdgcn_mfma_f32_16x16x32_bf16(afr, bfr[t], acc[u][t], 0, 0, 0);
            }
        }
#pragma unroll
        for (int u = 0; u < 4; ++u)
#pragma unroll
            for (int t = 0; t < 4; ++t)
#pragma unroll
                for (int r = 0; r < 4; ++r) {
                    int c = cb + u * 16 + lg * 4 + r;
                    vws[((size_t)b * CC + c) * NN + i0 + t * 16 + lr] = f2bf(acc[u][t][r]);
                }
    }
}

// ---------------- kernel 2: flash attention + residual ----------------
// 512 blocks (2/CU), 8 waves. Block = (batch, 64q, 128c-half).
// S: 16x16 swapped QK^T, roles (a=w&3 q-tile, h=w>>2 j-half) -- zero in-block
// redundancy, balanced (R7 scheme). In-register exp; P -> LDS (swz8 XOR).
// PV: 32x32x16, wave owns 32c x 32q (cs=w&3, qhp=w>>2); V comes from L2
// straight into registers (double-buffered, issued one iter early) -- no V
// LDS traffic at all. K staged via global_load_lds, double-buffered.
// Barrier A: LDS-only (P visibility). Barrier B: vmcnt(4) (drain K stage,
// keep 4 V loads in flight) + lgkmcnt(0) (P-read WAR).
__global__ __launch_bounds__(512, 4) void k_attn(
        const unsigned short* __restrict__ q_hi, const unsigned short* __restrict__ q_lo,
        const unsigned short* __restrict__ k_hi, const unsigned short* __restrict__ k_lo,
        const unsigned short* __restrict__ vws,
        const float* __restrict__ x, float* __restrict__ out) {
    __shared__ __align__(16) unsigned short K2[2][4096];  // [j64][slot8][8] hi0-3/lo4-7
    __shared__ __align__(16) unsigned short Pt[4096];     // [q64][slot8][8]
    __shared__ float lsum_s[2][64];                       // [jh][q]

    int m = blockIdx.x;
    int xcd = m & 7;                 // XCD pair {2b,2b+1} serves batch b
    int b = xcd >> 1;
    int t128 = ((m >> 3) << 1) + (xcd & 1);
    int qblk = t128 >> 1;            // 0..63
    int hc = t128 & 1;               // c-half
    int i0 = qblk * 64;
    int cb0 = hc * 128;
    int tid = threadIdx.x, w = tid >> 6, lane = tid & 63;
    int lr = lane & 15, lg = lane >> 4, lr7 = lr & 7;
    int a = w & 3, h = w >> 2;       // S roles
    int l31 = lane & 31, hh = lane >> 5;
    int cs = w & 3, qhp = w >> 2;    // PV roles

    // Q fragments (B-operand): lane holds Q[q = i0+a*16+lr][d = lg*8+e]
    bf8 qfh, qfl;
    {
        size_t off = ((size_t)b * NN + i0 + a * 16 + lr) * CO + lg * 8;
        qfh = *(const bf8*)(q_hi + off);
        qfl = *(const bf8*)(q_lo + off);
    }

    // K stage source (pre-swizzled involution: phys slot sl holds chunk sl^row&7)
    int l3 = lane >> 3, sl = lane & 7;
    int usK = sl ^ l3;
    const unsigned short* kbase = (usK < 4) ? (k_hi + (size_t)b * NN * CO + usK * 8)
                                            : (k_lo + (size_t)b * NN * CO + (usK - 4) * 8);
    const unsigned short* ksrc = kbase + (size_t)(w * 8 + l3) * CO;
    auto stageK = [&](int jt, int p) {
        int j0 = ((jt < 64) ? jt : 63) * 64;
        __builtin_amdgcn_global_load_lds((const AS1 void*)(ksrc + (size_t)j0 * CO),
            (AS3 void*)(&K2[p][(w * 8) * 64]), 16, 0, 0);
    };

    // V A-fragment source: lane (l31,hh) reads V^T[c=cb0+cs*32+l31][j=j0+kc*16+hh*8]
    const unsigned short* vsrcb = vws + ((size_t)b * CC + cb0 + cs * 32 + l31) * NN + hh * 8;

    f16f acc = {};
    float lsum = 0.f;
    bf8 vA[4], vB[4];

    stageK(0, 0);
#pragma unroll
    for (int kc = 0; kc < 4; ++kc) vA[kc] = *(const bf8*)(vsrcb + kc * 16);
    __syncthreads();

    auto iter = [&](int jt, bf8 (&vc)[4], bf8 (&vn)[4]) {
        int p = jt & 1;
        stageK(jt + 1, p ^ 1);          // oldest outstanding; drained at barrier B
        // ---- S^T = K·Q^T (16x16 split precision) + exp + pack P ----
#pragma unroll
        for (int t = 0; t < 2; ++t) {
            int jl = h * 32 + t * 16 + lr;
            const unsigned short* Kp = &K2[p][jl * 64];
            bf8 kfh = *(const bf8*)(Kp + ((lg ^ lr7)) * 8);
            bf8 kfl = *(const bf8*)(Kp + (((4 | lg) ^ lr7)) * 8);
            f4 s = {};
            s = __builtin_amdgcn_mfma_f32_16x16x32_bf16(kfh, qfl, s, 0, 0, 0);
            s = __builtin_amdgcn_mfma_f32_16x16x32_bf16(kfl, qfh, s, 0, 0, 0);
            s = __builtin_amdgcn_mfma_f32_16x16x32_bf16(kfh, qfh, s, 0, 0, 0);
            float e0 = __expf(s[0]), e1 = __expf(s[1]), e2 = __expf(s[2]), e3 = __expf(s[3]);
            lsum += (e0 + e1) + (e2 + e3);
            u32x2 d;
            d[0] = cvt_pk_bf16(e0, e1);
            d[1] = cvt_pk_bf16(e2, e3);
            int row = a * 16 + lr;
            int swz = (row ^ (row >> 3)) & 7;
            int slot = (h * 4 + t * 2 + (lg >> 1)) ^ swz;
            *(u32x2*)&Pt[row * 64 + slot * 8 + (lg & 1) * 4] = d;
        }
        LDS_BARRIER();                  // P visible; K stage stays in flight
        // ---- PV: acc += V(A, regs) x P(B, LDS), 32x32x16, full 64-j ----
        __builtin_amdgcn_s_setprio(1);
        {
            int prow = qhp * 32 + l31;
            int pswz = (prow ^ (prow >> 3)) & 7;
            const unsigned short* Pr = &Pt[prow * 64];
#pragma unroll
            for (int kc = 0; kc < 4; ++kc) {
                bf8 pb = *(const bf8*)(Pr + (((kc * 2 + hh) ^ pswz)) * 8);
                acc = __builtin_amdgcn_mfma_f32_32x32x16_bf16(vc[kc], pb, acc, 0, 0, 0);
            }
        }
        __builtin_amdgcn_s_setprio(0);
        // issue V(jt+1) into the other register set (in flight across barrier)
        {
            int j0n = ((jt + 1 < 64) ? (jt + 1) : 63) * 64;
#pragma unroll
            for (int kc = 0; kc < 4; ++kc)
                vn[kc] = *(const bf8*)(vsrcb + j0n + kc * 16);
        }
        // ---- barrier B: drain K(jt+1) (oldest), keep 4 V loads in flight ----
        __builtin_amdgcn_sched_barrier(0);
        asm volatile("s_waitcnt vmcnt(4) lgkmcnt(0)" ::: "memory");
        __builtin_amdgcn_s_barrier();
        __builtin_amdgcn_sched_barrier(0);
    };

    for (int jt = 0; jt < 64; jt += 2) {
        iter(jt, vA, vB);
        iter(jt + 1, vB, vA);
    }

    // denominator: lane (lr,lg) covered q=a*16+lr, j-half h; reduce over lg
    lsum += __shfl_xor(lsum, 16, 64);
    lsum += __shfl_xor(lsum, 32, 64);
    if (lane < 16) lsum_s[h][a * 16 + lane] = lsum;
    __syncthreads();

    // epilogue: O^T * linv + residual (32x32 C/D layout: col=l31, row per reg)
    float linv = 1.0f / (lsum_s[0][qhp * 32 + l31] + lsum_s[1][qhp * 32 + l31]);
    int iq = i0 + qhp * 32 + l31;
#pragma unroll
    for (int r = 0; r < 16; ++r) {
        int c = cb0 + cs * 32 + (r & 3) + 8 * (r >> 2) + 4 * hh;
        size_t off = ((size_t)(b * CC + c)) * NN + iq;
        out[off] = acc[r] * linv + x[off];
    }
}

extern "C" void kernel_launch(void* const* d_in, const int* in_sizes, int n_in,
                              void* d_out, int out_size, void* d_ws, size_t ws_size,
                              hipStream_t stream) {
    const float* x  = (const float*)d_in[0];
    const float* wq = (const float*)d_in[1];
    const float* bq = (const float*)d_in[2];
    const float* wk = (const float*)d_in[3];
    const float* bk = (const float*)d_in[4];
    const float* wv = (const float*)d_in[5];
    const float* bv = (const float*)d_in[6];
    float* out = (float*)d_out;
    char* ws = (char*)d_ws;
    // ws: qh 1MB | ql 1MB | kh 1MB | kl 1MB | v 8MB
    unsigned short* qh = (unsigned short*)(ws);
    unsigned short* ql = (unsigned short*)(ws + 1048576);
    unsigned short* kh = (unsigned short*)(ws + 2097152);
    unsigned short* kl = (unsigned short*)(ws + 3145728);
    unsigned short* vv = (unsigned short*)(ws + 4194304);

    hipLaunchKernelGGL(k_prep, dim3(256), dim3(512), 0, stream,
                       x, wq, bq, wk, bk, wv, bv, qh, ql, kh, kl, vv);
    hipLaunchKernelGGL(k_attn, dim3(512), dim3(512), 0, stream,
                       qh, ql, kh, kl, vv, x, out);
}

// Round 10
// 103.549 us; speedup vs baseline: 1.4995x; 1.4995x over previous
//
#include <hip/hip_runtime.h>
#include <cstdint>
#include <cstddef>

#define BB 4
#define CC 256
#define NN 4096
#define CO 32

typedef __attribute__((ext_vector_type(8))) short bf8;
typedef __attribute__((ext_vector_type(4))) float f4;
typedef __attribute__((ext_vector_type(16))) float f16f;
typedef __attribute__((ext_vector_type(2))) unsigned int u32x2;

#define AS1 __attribute__((address_space(1)))
#define AS3 __attribute__((address_space(3)))

__device__ __forceinline__ unsigned short f2bf(float f) {
    union { float f; unsigned int u; } c; c.f = f;
    unsigned int r = c.u + 0x7FFFu + ((c.u >> 16) & 1u);
    return (unsigned short)(r >> 16);
}
__device__ __forceinline__ float bf2f(unsigned short b) {
    union { unsigned int u; float f; } c; c.u = ((unsigned int)b) << 16;
    return c.f;
}
__device__ __forceinline__ unsigned int cvt_pk_bf16(float a, float b) {
    unsigned int r;
    asm("v_cvt_pk_bf16_f32 %0, %1, %2" : "=v"(r) : "v"(a), "v"(b));
    return r;
}

// ---------------- kernel 1: fused prep (transpose + QK-proj + V-proj) -------
__global__ __launch_bounds__(512, 2) void k_prep(
        const float* __restrict__ x,
        const float* __restrict__ wq, const float* __restrict__ bq,
        const float* __restrict__ wk, const float* __restrict__ bk,
        const float* __restrict__ wv, const float* __restrict__ bv,
        unsigned short* __restrict__ q_hi, unsigned short* __restrict__ q_lo,
        unsigned short* __restrict__ k_hi, unsigned short* __restrict__ k_lo,
        unsigned short* __restrict__ vws) {
    __shared__ float xT[64 * 256];   // (i,c) at i*256 + ((c>>2)^(i&7))*4 + (c&3)
    int blk = blockIdx.x;
    int it = blk & 63, b = blk >> 6;
    int i0 = it * 64;
    int tid = threadIdx.x, w = tid >> 6, lane = tid & 63;
    int lr = lane & 15, lg = lane >> 4;

    // phase 1: load + swizzled transpose
    {
        const float* xp = x + (size_t)b * CC * NN + i0;
        int cl = tid >> 4;            // 0..31
        int il = (tid & 15) * 4;      // 0..60
#pragma unroll
        for (int pass = 0; pass < 8; ++pass) {
            int c = pass * 32 + cl;
            f4 v = *(const f4*)(xp + (size_t)c * NN + il);
#pragma unroll
            for (int jj = 0; jj < 4; ++jj) {
                int i = il + jj;
                xT[i * 256 + (((c >> 2) ^ (i & 7)) << 2) + (c & 3)] = v[jj];
            }
        }
    }
    __syncthreads();

    if (w < 4) {
        // ---- Q/K projection, wave w -> local i rows [w*16, w*16+16) ----
        f4 acc[4] = {};
        for (int ks = 0; ks < 8; ++ks) {
            int i = w * 16 + lr;
            int kc = ks * 32 + lg * 8;
            f4 xa = *(const f4*)&xT[i * 256 + (((kc >> 2) ^ (i & 7)) << 2)];
            f4 xb = *(const f4*)&xT[i * 256 + ((((kc >> 2) + 1) ^ (i & 7)) << 2)];
            bf8 ahi, alo;
#pragma unroll
            for (int e = 0; e < 8; ++e) {
                float f = (e < 4) ? xa[e] : xb[e - 4];
                unsigned short hh = f2bf(f);
                ahi[e] = (short)hh;
                alo[e] = (short)f2bf(f - bf2f(hh));
            }
#pragma unroll
            for (int u = 0; u < 4; ++u) {
                int o = u * 16 + lr;
                const float* wrow = (u < 2) ? (wq + (size_t)o * CC)
                                            : (wk + (size_t)(o - 32) * CC);
                bf8 bhi, blo;
#pragma unroll
                for (int e = 0; e < 8; ++e) {
                    float wvv = wrow[ks * 32 + lg * 8 + e];
                    unsigned short hh = f2bf(wvv);
                    bhi[e] = (short)hh;
                    blo[e] = (short)f2bf(wvv - bf2f(hh));
                }
                acc[u] = __builtin_amdgcn_mfma_f32_16x16x32_bf16(alo, bhi, acc[u], 0, 0, 0);
                acc[u] = __builtin_amdgcn_mfma_f32_16x16x32_bf16(ahi, blo, acc[u], 0, 0, 0);
                acc[u] = __builtin_amdgcn_mfma_f32_16x16x32_bf16(ahi, bhi, acc[u], 0, 0, 0);
            }
        }
#pragma unroll
        for (int u = 0; u < 4; ++u) {
            int o = u * 16 + lr;
            float bias = (u < 2) ? bq[o] : bk[o - 32];
#pragma unroll
            for (int r = 0; r < 4; ++r) {
                int i = i0 + w * 16 + lg * 4 + r;
                float v = acc[u][r] + bias;
                unsigned short hh = f2bf(v);
                unsigned short ll = f2bf(v - bf2f(hh));
                if (u < 2) {
                    size_t off = ((size_t)b * NN + i) * CO + o;
                    q_hi[off] = hh; q_lo[off] = ll;
                } else {
                    size_t off = ((size_t)b * NN + i) * CO + (o - 32);
                    k_hi[off] = hh; k_lo[off] = ll;
                }
            }
        }
    } else {
        // ---- V projection, wave (w-4) -> c rows [(w-4)*64, +64) ----
        int cb = (w - 4) * 64;
        f4 acc[4][4];   // [u c-sub][t i-sub]
#pragma unroll
        for (int u = 0; u < 4; ++u) {
            f4 bias4;
#pragma unroll
            for (int r = 0; r < 4; ++r) bias4[r] = bv[cb + u * 16 + lg * 4 + r];
#pragma unroll
            for (int t = 0; t < 4; ++t) acc[u][t] = bias4;
        }
        for (int ks = 0; ks < 8; ++ks) {
            bf8 bfr[4];
#pragma unroll
            for (int t = 0; t < 4; ++t) {
                int i = t * 16 + lr;
                int kc = ks * 32 + lg * 8;
                f4 xa = *(const f4*)&xT[i * 256 + (((kc >> 2) ^ (i & 7)) << 2)];
                f4 xb = *(const f4*)&xT[i * 256 + ((((kc >> 2) + 1) ^ (i & 7)) << 2)];
#pragma unroll
                for (int e = 0; e < 8; ++e)
                    bfr[t][e] = (short)f2bf((e < 4) ? xa[e] : xb[e - 4]);
            }
#pragma unroll
            for (int u = 0; u < 4; ++u) {
                const float* wrow = wv + (size_t)(cb + u * 16 + lr) * CC + ks * 32 + lg * 8;
                bf8 afr;
#pragma unroll
                for (int e = 0; e < 8; ++e) afr[e] = (short)f2bf(wrow[e]);
#pragma unroll
                for (int t = 0; t < 4; ++t)
                    acc[u][t] = __builtin_amdgcn_mfma_f32_16x16x32_bf16(afr, bfr[t], acc[u][t], 0, 0, 0);
            }
        }
#pragma unroll
        for (int u = 0; u < 4; ++u)
#pragma unroll
            for (int t = 0; t < 4; ++t)
#pragma unroll
                for (int r = 0; r < 4; ++r) {
                    int c = cb + u * 16 + lg * 4 + r;
                    vws[((size_t)b * CC + c) * NN + i0 + t * 16 + lr] = f2bf(acc[u][t][r]);
                }
    }
}

// ---------------- kernel 2: flash attention + residual ----------------
// 512 blocks (2/CU), 8 waves. Block = (batch, 32q tile, ALL 256 channels).
// q-split: zero S/exp duplication (was 2x under c-split). S: wave role
// (qh=w&1, jq=w>>1) computes one 16q x 16j tile, swapped QK^T, in-register
// exp, P -> single-buffer LDS. PV: wave w owns c=[w*32,w*32+32) x 32q via
// verified 32x32x16 fragments, V from double-buffered LDS (global_load_lds,
// pre-swizzled involution), K single-buffered (staged in the A->B window).
// Barrier A: vmcnt(0)+lgkm(0)  (V(jt) staged one full phase ago lands; P vis)
// Barrier B: vmcnt(4)+lgkm(0)  (drain K(jt+1), keep 4 V(jt+1) in flight)
__global__ __launch_bounds__(512, 4) void k_attn(
        const unsigned short* __restrict__ q_hi, const unsigned short* __restrict__ q_lo,
        const unsigned short* __restrict__ k_hi, const unsigned short* __restrict__ k_lo,
        const unsigned short* __restrict__ vws,
        const float* __restrict__ x, float* __restrict__ out) {
    __shared__ __align__(16) unsigned short Vt[2][16384];  // [p][c256][slot8][8] 32KB each
    __shared__ __align__(16) unsigned short K2[4096];      // [j64][slot8][8] hi0-3/lo4-7 8KB
    __shared__ __align__(16) unsigned short Pt[2048];      // [q32][slot8][8] 4KB
    __shared__ float lsum_s[4][32];                        // [jq][q]

    int m = blockIdx.x;
    int xcd = m & 7;                 // XCD pair {2b,2b+1} serves batch b
    int b = xcd >> 1;
    int qblk = ((m >> 3) << 1) + (xcd & 1);   // 0..127
    int i0 = qblk * 32;
    int tid = threadIdx.x, w = tid >> 6, lane = tid & 63;
    int lr = lane & 15, lg = lane >> 4, lr7 = lr & 7;
    int qh = w & 1, jq = w >> 1;     // S roles: 16q x 16j tile
    int l31 = lane & 31, hh = lane >> 5;

    // Q fragments (B-operand): lane holds Q[q = i0+qh*16+lr][d = lg*8+e]
    bf8 qfh, qfl;
    {
        size_t off = ((size_t)b * NN + i0 + qh * 16 + lr) * CO + lg * 8;
        qfh = *(const bf8*)(q_hi + off);
        qfl = *(const bf8*)(q_lo + off);
    }

    // stage sources (pre-swizzled involution: phys slot sl holds chunk sl^(row&7))
    int l3 = lane >> 3, sl = lane & 7;
    int us = sl ^ l3;
    const unsigned short* kbase = (us < 4) ? (k_hi + (size_t)b * NN * CO + us * 8)
                                           : (k_lo + (size_t)b * NN * CO + (us - 4) * 8);
    const unsigned short* ksrc = kbase + (size_t)(w * 8 + l3) * CO;
    const unsigned short* vsrc = vws + ((size_t)b * CC + w * 32 + l3) * NN + us * 8;

    auto stageK = [&](int jt) {
        int j0 = ((jt < 64) ? jt : 63) * 64;
        __builtin_amdgcn_global_load_lds((const AS1 void*)(ksrc + (size_t)j0 * CO),
            (AS3 void*)(&K2[(w * 8) * 64]), 16, 0, 0);
    };
    auto stageV = [&](int jt, int p) {
        int j0 = ((jt < 64) ? jt : 63) * 64;
#pragma unroll
        for (int n = 0; n < 4; ++n) {
            __builtin_amdgcn_global_load_lds((const AS1 void*)(vsrc + (size_t)(n * 8) * NN + j0),
                (AS3 void*)(&Vt[p][(w * 32 + n * 8) * 64]), 16, 0, 0);
        }
    };

    f16f acc = {};            // O^T 32c x 32q tile: col q = l31, rows c per reg
    float lsum = 0.f;

    stageK(0);
    stageV(0, 0);
    __syncthreads();          // full drain

    int prow_swz = (l31 ^ (l31 >> 3)) & 7;   // P-read swizzle (row = q = l31)
    int vrow_swz = l31 & 7;                  // V-read swizzle (row&7)

    for (int jt = 0; jt < 64; ++jt) {
        int pv = jt & 1;
        // ---- S-phase: S^T = K·Q^T (16x16 split) + exp + pack P ----
        {
            int jl = jq * 16 + lr;
            const unsigned short* Kp = &K2[jl * 64];
            bf8 kfh = *(const bf8*)(Kp + ((lg ^ lr7)) * 8);
            bf8 kfl = *(const bf8*)(Kp + (((4 | lg) ^ lr7)) * 8);
            f4 s = {};
            s = __builtin_amdgcn_mfma_f32_16x16x32_bf16(kfh, qfl, s, 0, 0, 0);
            s = __builtin_amdgcn_mfma_f32_16x16x32_bf16(kfl, qfh, s, 0, 0, 0);
            s = __builtin_amdgcn_mfma_f32_16x16x32_bf16(kfh, qfh, s, 0, 0, 0);
            float e0 = __expf(s[0]), e1 = __expf(s[1]), e2 = __expf(s[2]), e3 = __expf(s[3]);
            lsum += (e0 + e1) + (e2 + e3);
            u32x2 d;
            d[0] = cvt_pk_bf16(e0, e1);
            d[1] = cvt_pk_bf16(e2, e3);
            int row = qh * 16 + lr;                       // q-local 0..31
            int swz = (row ^ (row >> 3)) & 7;
            int slot = (jq * 2 + (lg >> 1)) ^ swz;
            *(u32x2*)&Pt[row * 64 + slot * 8 + (lg & 1) * 4] = d;
        }
        // ---- barrier A: V(jt) landed (staged one full phase ago); P visible
        __builtin_amdgcn_sched_barrier(0);
        asm volatile("s_waitcnt vmcnt(0) lgkmcnt(0)" ::: "memory");
        __builtin_amdgcn_s_barrier();
        __builtin_amdgcn_sched_barrier(0);
        // stage K(jt+1) into the single K buffer (all its readers are pre-A)
        stageK(jt + 1);
        // ---- PV: acc += V(A) x P(B), 32x32x16, full 64-j contraction ----
        __builtin_amdgcn_s_setprio(1);
        {
            const unsigned short* Pr = &Pt[l31 * 64];
            const unsigned short* Vr = &Vt[pv][(w * 32 + l31) * 64];
#pragma unroll
            for (int kc = 0; kc < 4; ++kc) {
                bf8 pb = *(const bf8*)(Pr + (((kc * 2 + hh) ^ prow_swz)) * 8);
                bf8 vf = *(const bf8*)(Vr + (((kc * 2 + hh) ^ vrow_swz)) * 8);
                acc = __builtin_amdgcn_mfma_f32_32x32x16_bf16(vf, pb, acc, 0, 0, 0);
            }
        }
        __builtin_amdgcn_s_setprio(0);
        // stage V(jt+1) into the other buffer (reads of it finished pre-B(jt-1))
        stageV(jt + 1, pv ^ 1);
        // ---- barrier B: drain K(jt+1) only (vmcnt(4): 4 V-stages in flight);
        //      P reads done (lgkm) so next S-phase may overwrite Pt
        __builtin_amdgcn_sched_barrier(0);
        asm volatile("s_waitcnt vmcnt(4) lgkmcnt(0)" ::: "memory");
        __builtin_amdgcn_s_barrier();
        __builtin_amdgcn_sched_barrier(0);
    }

    // denominator: lane covered q=qh*16+lr, j-slice (jq, lg); reduce over lg
    lsum += __shfl_xor(lsum, 16, 64);
    lsum += __shfl_xor(lsum, 32, 64);
    if (lane < 16) lsum_s[jq][qh * 16 + lane] = lsum;
    __syncthreads();

    // epilogue: O^T * linv + residual (32x32 C/D: col q = l31, row c per reg)
    float linv = 1.0f / (((lsum_s[0][l31] + lsum_s[1][l31]) +
                          (lsum_s[2][l31] + lsum_s[3][l31])));
    int iq = i0 + l31;
#pragma unroll
    for (int r = 0; r < 16; ++r) {
        int c = w * 32 + (r & 3) + 8 * (r >> 2) + 4 * hh;
        size_t off = ((size_t)(b * CC + c)) * NN + iq;
        out[off] = acc[r] * linv + x[off];
    }
}

extern "C" void kernel_launch(void* const* d_in, const int* in_sizes, int n_in,
                              void* d_out, int out_size, void* d_ws, size_t ws_size,
                              hipStream_t stream) {
    const float* x  = (const float*)d_in[0];
    const float* wq = (const float*)d_in[1];
    const float* bq = (const float*)d_in[2];
    const float* wk = (const float*)d_in[3];
    const float* bk = (const float*)d_in[4];
    const float* wv = (const float*)d_in[5];
    const float* bv = (const float*)d_in[6];
    float* out = (float*)d_out;
    char* ws = (char*)d_ws;
    // ws: qh 1MB | ql 1MB | kh 1MB | kl 1MB | v 8MB
    unsigned short* qh = (unsigned short*)(ws);
    unsigned short* ql = (unsigned short*)(ws + 1048576);
    unsigned short* kh = (unsigned short*)(ws + 2097152);
    unsigned short* kl = (unsigned short*)(ws + 3145728);
    unsigned short* vv = (unsigned short*)(ws + 4194304);

    hipLaunchKernelGGL(k_prep, dim3(256), dim3(512), 0, stream,
                       x, wq, bq, wk, bk, wv, bv, qh, ql, kh, kl, vv);
    hipLaunchKernelGGL(k_attn, dim3(512), dim3(512), 0, stream,
                       qh, ql, kh, kl, vv, x, out);
}